// Round 13
// baseline (47.791 us; speedup 1.0000x reference)
//
#include <hip/hip_runtime.h>
#include <math.h>

#define BATCH 8192
#define NLEN 4096
#define THREADS 256
#define PER_THREAD (NLEN / THREADS)  // 16
#define RPB 4                        // rows per block (grid-stride)
#define NBLK (BATCH / RPB)           // 2048 blocks

// ---------------------------------------------------------------------------
// Kernel 1: 2048 blocks x 256 threads, 4 ROWS PER BLOCK with SOFTWARE
// PREFETCH: row r+1's 4 float4 loads are issued before row r's compute, so
// global loads stay in flight across the per-row barriers (vmcnt survives
// s_barrier) and the memory pipe never idles during compute/reduce phases.
// Per-row machinery identical to round-10/12 (best measured): 16 contiguous
// elements per thread, LDS scan-back for compaction boundaries, f32 partials
// -> f64 block reduction. LDS double-buffered by row parity (2 barriers/row,
// reuse distance 4 barriers -> no hazards). XCD-contiguous bijective swizzle
// (2048 = 8 x 256): each XCD streams a contiguous 16 MB slab. feats written
// COLUMN-MAJOR for k2's coalesced stats walk.
// ---------------------------------------------------------------------------
__global__ __launch_bounds__(THREADS) void hrv_feats_kernel(
    const float* __restrict__ rr, float* __restrict__ feats) {
    __shared__ float sh_last[2][THREADS];
    __shared__ unsigned char sh_has[2][THREADS];
    __shared__ double sh_sum[2][4], sh_sumsq[2][4], sh_sumd2[2][4];
    __shared__ int sh_cnt[2][4], sh_nn50[2][4];

    const int t = threadIdx.x;
    // bijective XCD swizzle: XCD (bid&7) gets contiguous chunks
    const int chunk = ((blockIdx.x & 7) << 8) | (blockIdx.x >> 3);
    const int row0 = chunk * RPB;
    const float* base = rr + (size_t)row0 * NLEN + t * PER_THREAD;

    float x[2][PER_THREAD];
    // preload row 0
    {
        const float4* rv = reinterpret_cast<const float4*>(base);
        float4* xv = reinterpret_cast<float4*>(x[0]);
#pragma unroll
        for (int i = 0; i < PER_THREAD / 4; ++i) xv[i] = rv[i];
    }

#pragma unroll
    for (int r = 0; r < RPB; ++r) {
        const int pb = r & 1;
        // prefetch row r+1 (issued before row r's compute; hides under it)
        if (r < RPB - 1) {
            const float4* rv =
                reinterpret_cast<const float4*>(base + (size_t)(r + 1) * NLEN);
            float4* xv = reinterpret_cast<float4*>(x[pb ^ 1]);
#pragma unroll
            for (int i = 0; i < PER_THREAD / 4; ++i) xv[i] = rv[i];
        }

        // ---- per-row feature machinery (round-10 body) on x[pb] ----
        float sum = 0.f, sumsq = 0.f, sumd2 = 0.f;
        int cnt = 0, nn50 = 0;
        float first = 0.f, last = 0.f;
        int has = 0;
#pragma unroll
        for (int i = 0; i < PER_THREAD; ++i) {
            float v = x[pb][i];
            if (v > 0.f) {
                sum += v;
                sumsq += v * v;
                ++cnt;
                if (has) {
                    float d = v - last;  // same f32 subtraction as reference
                    sumd2 += d * d;
                    nn50 += (fabsf(d) > 0.05f) ? 1 : 0;
                } else {
                    first = v;
                    has = 1;
                }
                last = v;
            }
        }
        sh_last[pb][t] = last;
        sh_has[pb][t] = (unsigned char)has;
        __syncthreads();
        if (has && t > 0) {
            for (int j = t - 1; j >= 0; --j) {
                if (sh_has[pb][j]) {
                    float d = first - sh_last[pb][j];
                    sumd2 += d * d;
                    nn50 += (fabsf(d) > 0.05f) ? 1 : 0;
                    break;
                }
            }
        }

        double dsum = sum, dsumsq = sumsq, dsumd2 = sumd2;
        int icnt = cnt, inn = nn50;
#pragma unroll
        for (int off = 32; off > 0; off >>= 1) {
            dsum += __shfl_down(dsum, off, 64);
            dsumsq += __shfl_down(dsumsq, off, 64);
            dsumd2 += __shfl_down(dsumd2, off, 64);
            icnt += __shfl_down(icnt, off, 64);
            inn += __shfl_down(inn, off, 64);
        }
        const int wave = t >> 6;
        if ((t & 63) == 0) {
            sh_sum[pb][wave] = dsum;
            sh_sumsq[pb][wave] = dsumsq;
            sh_sumd2[pb][wave] = dsumd2;
            sh_cnt[pb][wave] = icnt;
            sh_nn50[pb][wave] = inn;
        }
        __syncthreads();
        if (t == 0) {
            double S = 0, S2 = 0, D2 = 0;
            int C = 0, NN = 0;
#pragma unroll
            for (int w = 0; w < 4; ++w) {
                S += sh_sum[pb][w];
                S2 += sh_sumsq[pb][w];
                D2 += sh_sumd2[pb][w];
                C += sh_cnt[pb][w];
                NN += sh_nn50[pb][w];
            }
            const float cntf = (float)C;
            const float denom_m = fmaxf(cntf, 1.f);
            const float mean = (float)(S / (double)denom_m);
            const float varsum =
                (float)(S2 - (double)C * (double)mean * (double)mean);
            const float denom_v = fmaxf(cntf - 1.f, 1.f);
            const float sdnn = sqrtf(fmaxf(varsum / denom_v, 0.f));
            const float rmssd = sqrtf(fmaxf((float)(D2 / (double)denom_v), 0.f));
            const float pnn50 = (float)NN / denom_v;
            const float hr = 60.f / fmaxf(mean, 1e-12f);
            const float cv = sdnn / fmaxf(mean, 1e-12f);
            float f[6] = {mean, sdnn, rmssd, pnn50, hr, cv};
            if (C <= 1) {
#pragma unroll
                for (int c = 0; c < 6; ++c) f[c] = 0.f;
            }
            const int row = row0 + r;
#pragma unroll
            for (int c = 0; c < 6; ++c) feats[c * BATCH + row] = f[c];
        }
    }
}

// ---------------------------------------------------------------------------
// Kernel 2 (round-12 body): fused col-stats + MLP, 32 blocks x 256 threads.
// Weights staged into LDS first (latency overlaps the stats walk). Stats:
// column-major feats read as 3 rounds of 16 in-flight float4; f64 accum for
// the catastrophic (sumsq - B*mean^2) cancellation; deterministic identical
// stats per block. Then normalize + 6->16 ReLU -> 32 MLP, one row/thread.
// ---------------------------------------------------------------------------
__global__ __launch_bounds__(256) void stats_mlp_kernel(
    const float* __restrict__ feats,
    const float* __restrict__ w1, const float* __restrict__ b1,
    const float* __restrict__ w2, const float* __restrict__ b2,
    float* __restrict__ out) {
    __shared__ float sh_w[656];  // w1(96) b1(16) w2(512) b2(32)
    __shared__ double sh_s[4][6], sh_s2[4][6];
    __shared__ float sh_m[4][6];
    __shared__ float sh_stats[18];  // mean[6], std[6], max[6]

    const int t = threadIdx.x;

    // stage weights into LDS (issued first; latency hides under stats walk)
    for (int i = t; i < 656; i += 256) {
        float v;
        if (i < 96) v = w1[i];
        else if (i < 112) v = b1[i - 96];
        else if (i < 624) v = w2[i - 112];
        else v = b2[i - 624];
        sh_w[i] = v;
    }

    // ---- stats: 3 rounds x 16 in-flight float4 over col-major feats ----
    double s[6], s2[6];
    float mx[6];
#pragma unroll
    for (int c = 0; c < 6; ++c) { s[c] = 0.0; s2[c] = 0.0; mx[c] = -INFINITY; }

#pragma unroll
    for (int cp = 0; cp < 3; ++cp) {
        const float4* c0 =
            reinterpret_cast<const float4*>(feats + (2 * cp) * BATCH);
        const float4* c1 =
            reinterpret_cast<const float4*>(feats + (2 * cp + 1) * BATCH);
        float4 buf[16];
#pragma unroll
        for (int k = 0; k < 8; ++k) buf[k] = c0[t + k * 256];
#pragma unroll
        for (int k = 0; k < 8; ++k) buf[8 + k] = c1[t + k * 256];
#pragma unroll
        for (int k = 0; k < 16; ++k) {
            const int c = 2 * cp + (k >> 3);
            const float f[4] = {buf[k].x, buf[k].y, buf[k].z, buf[k].w};
#pragma unroll
            for (int e = 0; e < 4; ++e) {
                s[c] += (double)f[e];
                s2[c] += (double)f[e] * (double)f[e];
                mx[c] = fmaxf(mx[c], f[e]);
            }
        }
    }
#pragma unroll
    for (int off = 32; off; off >>= 1) {
#pragma unroll
        for (int c = 0; c < 6; ++c) {
            s[c] += __shfl_down(s[c], off, 64);
            s2[c] += __shfl_down(s2[c], off, 64);
            mx[c] = fmaxf(mx[c], __shfl_down(mx[c], off, 64));
        }
    }
    if ((t & 63) == 0) {
        const int w = t >> 6;
#pragma unroll
        for (int c = 0; c < 6; ++c) {
            sh_s[w][c] = s[c];
            sh_s2[w][c] = s2[c];
            sh_m[w][c] = mx[c];
        }
    }
    __syncthreads();
    if (t < 6) {
        double S = 0, S2 = 0;
        float M = -INFINITY;
        for (int w = 0; w < 4; ++w) {
            S += sh_s[w][t];
            S2 += sh_s2[w][t];
            M = fmaxf(M, sh_m[w][t]);
        }
        const double meanb = S / (double)BATCH;
        double var = (S2 - (double)BATCH * meanb * meanb) / (double)(BATCH - 1);
        if (var < 0.0) var = 0.0;
        sh_stats[t] = (float)meanb;
        sh_stats[6 + t] = (float)sqrt(var);
        sh_stats[12 + t] = M;
    }
    __syncthreads();

    // ---- MLP: one row per thread, weights from LDS ----
    const int row = blockIdx.x * 256 + t;
    float f[6];
#pragma unroll
    for (int c = 0; c < 6; ++c) {
        float v = feats[c * BATCH + row];  // coalesced across threads
        if (sh_stats[12 + c] > 0.f)
            v = (v - sh_stats[c]) / (sh_stats[6 + c] + 1e-8f);
        f[c] = v;
    }
    float h[16];
#pragma unroll
    for (int j = 0; j < 16; ++j) {
        float a = sh_w[96 + j];
#pragma unroll
        for (int c = 0; c < 6; ++c) a = fmaf(f[c], sh_w[c * 16 + j], a);
        h[j] = fmaxf(a, 0.f);
    }
    float o[32];
#pragma unroll
    for (int k = 0; k < 32; ++k) o[k] = sh_w[624 + k];
#pragma unroll
    for (int j = 0; j < 16; ++j) {
        const float hj = h[j];
#pragma unroll
        for (int k = 0; k < 32; ++k) o[k] = fmaf(hj, sh_w[112 + j * 32 + k], o[k]);
    }
    float4* ov = reinterpret_cast<float4*>(out + (size_t)row * 32);
    const float4* op = reinterpret_cast<const float4*>(o);
#pragma unroll
    for (int i = 0; i < 8; ++i) ov[i] = op[i];
}

extern "C" void kernel_launch(void* const* d_in, const int* in_sizes, int n_in,
                              void* d_out, int out_size, void* d_ws, size_t ws_size,
                              hipStream_t stream) {
    const float* rr = (const float*)d_in[0];
    const float* w1 = (const float*)d_in[1];
    const float* b1 = (const float*)d_in[2];
    const float* w2 = (const float*)d_in[3];
    const float* b2 = (const float*)d_in[4];
    float* out = (float*)d_out;
    float* feats = (float*)d_ws;  // column-major [6][BATCH] = 192 KiB

    hrv_feats_kernel<<<NBLK, THREADS, 0, stream>>>(rr, feats);
    stats_mlp_kernel<<<BATCH / 256, THREADS, 0, stream>>>(feats, w1, b1, w2, b2, out);
}

// Round 14
// 39.239 us; speedup vs baseline: 1.2180x; 1.2180x over previous
//
#include <hip/hip_runtime.h>
#include <math.h>

#define BATCH 8192
#define NLEN 4096
#define THREADS 256
#define PER_THREAD (NLEN / THREADS)  // 16

// ---------------------------------------------------------------------------
// Kernel 1 (round-12 config, best measured 39.2us): ONE BLOCK PER ROW, 16
// contiguous elements per thread (4x float4, fully coalesced). Compaction
// boundaries via LDS scan-back. f32 per-chunk partials -> f64 block
// reduction. XCD-contiguous block swizzle (8192 = 8 x 1024, bijective) so
// each XCD streams a contiguous 16 MB slab; feats written COLUMN-MAJOR so
// k2's stats walk is float4-coalesced.
// NOTE (round-13 lesson): do NOT pipeline rows within a block — inter-block
// TLP from 8192 tiny blocks already saturates the memory pipe; grid-stride
// row loops with prefetch regressed 39.2 -> 47.8us.
// ---------------------------------------------------------------------------
__global__ __launch_bounds__(THREADS) void hrv_feats_kernel(
    const float* __restrict__ rr, float* __restrict__ feats) {
    __shared__ float sh_last[THREADS];
    __shared__ unsigned char sh_has[THREADS];
    __shared__ double sh_sum[4], sh_sumsq[4], sh_sumd2[4];
    __shared__ int sh_cnt[4], sh_nn50[4];

    // XCD-aware swizzle: XCD (bid&7) gets contiguous rows [(bid&7)*1024 ...)
    const int row = ((blockIdx.x & 7) << 10) | (blockIdx.x >> 3);
    const int t = threadIdx.x;
    const float* r = rr + (size_t)row * NLEN + t * PER_THREAD;

    float x[PER_THREAD];
    float4* xv = reinterpret_cast<float4*>(x);
    const float4* rv = reinterpret_cast<const float4*>(r);
#pragma unroll
    for (int i = 0; i < PER_THREAD / 4; ++i) xv[i] = rv[i];

    float sum = 0.f, sumsq = 0.f, sumd2 = 0.f;
    int cnt = 0, nn50 = 0;
    float first = 0.f, last = 0.f;
    int has = 0;
#pragma unroll
    for (int i = 0; i < PER_THREAD; ++i) {
        float v = x[i];
        if (v > 0.f) {
            sum += v;
            sumsq += v * v;
            ++cnt;
            if (has) {
                float d = v - last;  // same f32 subtraction as reference
                sumd2 += d * d;
                nn50 += (fabsf(d) > 0.05f) ? 1 : 0;
            } else {
                first = v;
                has = 1;
            }
            last = v;
        }
    }
    sh_last[t] = last;
    sh_has[t] = (unsigned char)has;
    __syncthreads();
    // boundary diff: nearest preceding chunk with a valid element
    if (has && t > 0) {
        for (int j = t - 1; j >= 0; --j) {
            if (sh_has[j]) {
                float d = first - sh_last[j];
                sumd2 += d * d;
                nn50 += (fabsf(d) > 0.05f) ? 1 : 0;
                break;
            }
        }
    }

    double dsum = sum, dsumsq = sumsq, dsumd2 = sumd2;
    int icnt = cnt, inn = nn50;
#pragma unroll
    for (int off = 32; off > 0; off >>= 1) {
        dsum += __shfl_down(dsum, off, 64);
        dsumsq += __shfl_down(dsumsq, off, 64);
        dsumd2 += __shfl_down(dsumd2, off, 64);
        icnt += __shfl_down(icnt, off, 64);
        inn += __shfl_down(inn, off, 64);
    }
    const int wave = t >> 6;
    if ((t & 63) == 0) {
        sh_sum[wave] = dsum;
        sh_sumsq[wave] = dsumsq;
        sh_sumd2[wave] = dsumd2;
        sh_cnt[wave] = icnt;
        sh_nn50[wave] = inn;
    }
    __syncthreads();
    if (t == 0) {
        double S = 0, S2 = 0, D2 = 0;
        int C = 0, NN = 0;
        for (int w = 0; w < 4; ++w) {
            S += sh_sum[w];
            S2 += sh_sumsq[w];
            D2 += sh_sumd2[w];
            C += sh_cnt[w];
            NN += sh_nn50[w];
        }
        const float cntf = (float)C;
        const float denom_m = fmaxf(cntf, 1.f);
        const float mean = (float)(S / (double)denom_m);
        const float varsum = (float)(S2 - (double)C * (double)mean * (double)mean);
        const float denom_v = fmaxf(cntf - 1.f, 1.f);
        const float sdnn = sqrtf(fmaxf(varsum / denom_v, 0.f));
        const float rmssd = sqrtf(fmaxf((float)(D2 / (double)denom_v), 0.f));
        const float pnn50 = (float)NN / denom_v;
        const float hr = 60.f / fmaxf(mean, 1e-12f);
        const float cv = sdnn / fmaxf(mean, 1e-12f);
        float f[6] = {mean, sdnn, rmssd, pnn50, hr, cv};
        if (C <= 1) {
#pragma unroll
            for (int c = 0; c < 6; ++c) f[c] = 0.f;
        }
#pragma unroll
        for (int c = 0; c < 6; ++c) feats[c * BATCH + row] = f[c];  // col-major
    }
}

// ---------------------------------------------------------------------------
// Kernel 2 (round-12 body): fused col-stats + MLP, 32 blocks x 256 threads.
// Weights staged into LDS first (latency overlaps the stats walk). Stats:
// column-major feats read as 3 rounds of 16 in-flight float4; f64 accum for
// the catastrophic (sumsq - B*mean^2) cancellation; deterministic identical
// stats per block. Then normalize + 6->16 ReLU -> 32 MLP, one row/thread.
// ---------------------------------------------------------------------------
__global__ __launch_bounds__(256) void stats_mlp_kernel(
    const float* __restrict__ feats,
    const float* __restrict__ w1, const float* __restrict__ b1,
    const float* __restrict__ w2, const float* __restrict__ b2,
    float* __restrict__ out) {
    __shared__ float sh_w[656];  // w1(96) b1(16) w2(512) b2(32)
    __shared__ double sh_s[4][6], sh_s2[4][6];
    __shared__ float sh_m[4][6];
    __shared__ float sh_stats[18];  // mean[6], std[6], max[6]

    const int t = threadIdx.x;

    // stage weights into LDS (issued first; latency hides under stats walk)
    for (int i = t; i < 656; i += 256) {
        float v;
        if (i < 96) v = w1[i];
        else if (i < 112) v = b1[i - 96];
        else if (i < 624) v = w2[i - 112];
        else v = b2[i - 624];
        sh_w[i] = v;
    }

    // ---- stats: 3 rounds x 16 in-flight float4 over col-major feats ----
    double s[6], s2[6];
    float mx[6];
#pragma unroll
    for (int c = 0; c < 6; ++c) { s[c] = 0.0; s2[c] = 0.0; mx[c] = -INFINITY; }

#pragma unroll
    for (int cp = 0; cp < 3; ++cp) {
        const float4* c0 =
            reinterpret_cast<const float4*>(feats + (2 * cp) * BATCH);
        const float4* c1 =
            reinterpret_cast<const float4*>(feats + (2 * cp + 1) * BATCH);
        float4 buf[16];
#pragma unroll
        for (int k = 0; k < 8; ++k) buf[k] = c0[t + k * 256];
#pragma unroll
        for (int k = 0; k < 8; ++k) buf[8 + k] = c1[t + k * 256];
#pragma unroll
        for (int k = 0; k < 16; ++k) {
            const int c = 2 * cp + (k >> 3);
            const float f[4] = {buf[k].x, buf[k].y, buf[k].z, buf[k].w};
#pragma unroll
            for (int e = 0; e < 4; ++e) {
                s[c] += (double)f[e];
                s2[c] += (double)f[e] * (double)f[e];
                mx[c] = fmaxf(mx[c], f[e]);
            }
        }
    }
#pragma unroll
    for (int off = 32; off; off >>= 1) {
#pragma unroll
        for (int c = 0; c < 6; ++c) {
            s[c] += __shfl_down(s[c], off, 64);
            s2[c] += __shfl_down(s2[c], off, 64);
            mx[c] = fmaxf(mx[c], __shfl_down(mx[c], off, 64));
        }
    }
    if ((t & 63) == 0) {
        const int w = t >> 6;
#pragma unroll
        for (int c = 0; c < 6; ++c) {
            sh_s[w][c] = s[c];
            sh_s2[w][c] = s2[c];
            sh_m[w][c] = mx[c];
        }
    }
    __syncthreads();
    if (t < 6) {
        double S = 0, S2 = 0;
        float M = -INFINITY;
        for (int w = 0; w < 4; ++w) {
            S += sh_s[w][t];
            S2 += sh_s2[w][t];
            M = fmaxf(M, sh_m[w][t]);
        }
        const double meanb = S / (double)BATCH;
        double var = (S2 - (double)BATCH * meanb * meanb) / (double)(BATCH - 1);
        if (var < 0.0) var = 0.0;
        sh_stats[t] = (float)meanb;
        sh_stats[6 + t] = (float)sqrt(var);
        sh_stats[12 + t] = M;
    }
    __syncthreads();

    // ---- MLP: one row per thread, weights from LDS ----
    const int row = blockIdx.x * 256 + t;
    float f[6];
#pragma unroll
    for (int c = 0; c < 6; ++c) {
        float v = feats[c * BATCH + row];  // coalesced across threads
        if (sh_stats[12 + c] > 0.f)
            v = (v - sh_stats[c]) / (sh_stats[6 + c] + 1e-8f);
        f[c] = v;
    }
    float h[16];
#pragma unroll
    for (int j = 0; j < 16; ++j) {
        float a = sh_w[96 + j];
#pragma unroll
        for (int c = 0; c < 6; ++c) a = fmaf(f[c], sh_w[c * 16 + j], a);
        h[j] = fmaxf(a, 0.f);
    }
    float o[32];
#pragma unroll
    for (int k = 0; k < 32; ++k) o[k] = sh_w[624 + k];
#pragma unroll
    for (int j = 0; j < 16; ++j) {
        const float hj = h[j];
#pragma unroll
        for (int k = 0; k < 32; ++k) o[k] = fmaf(hj, sh_w[112 + j * 32 + k], o[k]);
    }
    float4* ov = reinterpret_cast<float4*>(out + (size_t)row * 32);
    const float4* op = reinterpret_cast<const float4*>(o);
#pragma unroll
    for (int i = 0; i < 8; ++i) ov[i] = op[i];
}

extern "C" void kernel_launch(void* const* d_in, const int* in_sizes, int n_in,
                              void* d_out, int out_size, void* d_ws, size_t ws_size,
                              hipStream_t stream) {
    const float* rr = (const float*)d_in[0];
    const float* w1 = (const float*)d_in[1];
    const float* b1 = (const float*)d_in[2];
    const float* w2 = (const float*)d_in[3];
    const float* b2 = (const float*)d_in[4];
    float* out = (float*)d_out;
    float* feats = (float*)d_ws;  // column-major [6][BATCH] = 192 KiB

    hrv_feats_kernel<<<BATCH, THREADS, 0, stream>>>(rr, feats);
    stats_mlp_kernel<<<BATCH / 256, THREADS, 0, stream>>>(feats, w1, b1, w2, b2, out);
}